// Round 6
// baseline (1614.333 us; speedup 1.0000x reference)
//
#include <hip/hip_runtime.h>
#include <math.h>

#define CC 32
typedef _Float16 f16;

static inline int cdiv(long long a, int b) { return (int)((a + b - 1) / b); }

union U8 { int4 i; f16 v[8]; };

// unpack 8 interleaved f16 (c*2+hd layout) -> two float4 (head0, head1)
__device__ inline void unpack8(const f16* p, float4& a0, float4& a1) {
  U8 u;
  u.i = *(const int4*)p;
  a0 = make_float4((float)u.v[0], (float)u.v[2], (float)u.v[4], (float)u.v[6]);
  a1 = make_float4((float)u.v[1], (float)u.v[3], (float)u.v[5], (float)u.v[7]);
}

// ---------- fp32 -> fp16 cast ----------
__global__ void k_cast(const float* __restrict__ x, f16* __restrict__ o, long long n) {
  long long i = (long long)blockIdx.x * blockDim.x + threadIdx.x;
  if (i < n) o[i] = (f16)x[i];
}

// ---------- degree histogram ----------
__global__ void k_degcnt(const int* __restrict__ src, const int* __restrict__ dst,
                         float* __restrict__ deg, int* __restrict__ cnt, int E) {
  int i = blockIdx.x * blockDim.x + threadIdx.x;
  if (i < E) {
    atomicAdd(&deg[src[i]], 1.0f);
    atomicAdd(&cnt[dst[i]], 1);
  }
}

__global__ void k_dis(float* __restrict__ dis, int N) {
  int i = blockIdx.x * blockDim.x + threadIdx.x;
  if (i < N) {
    float d = dis[i];
    dis[i] = (d > 0.f) ? rsqrtf(fmaxf(d, 1.f)) : 0.f;
  }
}

// ---------- single-block exclusive scan ----------
__global__ void k_scan(const int* __restrict__ cnt, int* __restrict__ rowptr,
                       int* __restrict__ cur, int N) {
  const int T = 1024;
  __shared__ int ps[T];
  int t = threadIdx.x;
  int chunk = (N + T - 1) / T;
  int lo = t * chunk, hi = min(lo + chunk, N);
  int s = 0;
  for (int i = lo; i < hi; ++i) s += cnt[i];
  ps[t] = s;
  __syncthreads();
  for (int off = 1; off < T; off <<= 1) {
    int v = (t >= off) ? ps[t - off] : 0;
    __syncthreads();
    ps[t] += v;
    __syncthreads();
  }
  int run = (t == 0) ? 0 : ps[t - 1];
  for (int i = lo; i < hi; ++i) {
    rowptr[i] = run;
    cur[i] = run;
    run += cnt[i];
  }
  if (t == T - 1) rowptr[N] = run;
}

// ---------- CSR fill (col only) ----------
__global__ void k_fill(const int* __restrict__ src, const int* __restrict__ dst,
                       int* __restrict__ cur, int* __restrict__ col, int E) {
  int i = blockIdx.x * blockDim.x + threadIdx.x;
  if (i < E) {
    int p = atomicAdd(&cur[dst[i]], 1);
    col[p] = src[i];
  }
}

// ---------- fused Cheb propagation (fp16 gather, 16-way unroll) + GEMM accumulate ----------
// inner = sum dis[s]*xh[s]; Tx = (-dis[g]*scale)*inner + prevscale*prev[g]
template <int FIRST>
__global__ void k_prop(const f16* __restrict__ xh, const float* __restrict__ xf,
                       const float* __restrict__ prev, const int* __restrict__ rowptr,
                       const int* __restrict__ col, const float* __restrict__ dis,
                       const float* __restrict__ W, const float* __restrict__ bias,
                       float* __restrict__ out, f16* __restrict__ outh,
                       float* __restrict__ chebacc, float scale, float prevscale, int N) {
  __shared__ float w0[1024];
  __shared__ float w1[FIRST ? 1024 : 1];
  for (int i = threadIdx.x; i < 1024; i += blockDim.x) {
    w0[i] = W[i];
    if (FIRST) w1[i] = W[1024 + i];
  }
  __syncthreads();
  int g = (blockIdx.x * blockDim.x + threadIdx.x) >> 5;
  int c = threadIdx.x & 31;
  if (g >= N) return;
  int lo = rowptr[g], hi = rowptr[g + 1];
  float disg = dis[g];
  float acc = 0.f;
  for (int j = lo; j < hi; j += 16) {
    int rem = hi - j;
    float xv[16], ww[16];
#pragma unroll
    for (int e = 0; e < 16; ++e) {
      int jj = (e < rem) ? (j + e) : j;
      int s = col[jj];
      ww[e] = (e < rem) ? dis[s] : 0.f;
      xv[e] = (float)xh[(long long)s * 32 + c];
    }
#pragma unroll
    for (int e = 0; e < 16; ++e) acc = fmaf(ww[e], xv[e], acc);
  }
  acc *= -disg * scale;
  if (!FIRST) acc = fmaf(prevscale, prev[(long long)g * 32 + c], acc);
  out[(long long)g * 32 + c] = acc;
  if (outh) outh[(long long)g * 32 + c] = (f16)acc;

  float o;
  if (FIRST) {
    o = bias[c];
    float p = xf[(long long)g * 32 + c];
#pragma unroll
    for (int cc = 0; cc < 32; ++cc) {
      float a = __shfl(p, cc, 32);
      o = fmaf(a, w0[cc * 32 + c], o);
    }
#pragma unroll
    for (int cc = 0; cc < 32; ++cc) {
      float a = __shfl(acc, cc, 32);
      o = fmaf(a, w1[cc * 32 + c], o);
    }
  } else {
    o = chebacc[(long long)g * 32 + c];
#pragma unroll
    for (int cc = 0; cc < 32; ++cc) {
      float a = __shfl(acc, cc, 32);
      o = fmaf(a, w0[cc * 32 + c], o);
    }
  }
  chebacc[(long long)g * 32 + c] = o;
}

// ---------- h = x @ lin_w, fp16 head-interleaved output: hh[row][c*2+hd] ----------
__global__ void k_gemm64(const float* __restrict__ T, const float* __restrict__ W,
                         f16* __restrict__ hh, int N) {
  __shared__ float w[2048];
  for (int i = threadIdx.x; i < 2048; i += blockDim.x) w[i] = W[i];
  __syncthreads();
  int row = blockIdx.x * 4 + threadIdx.x / 64;
  int colx = threadIdx.x % 64;  // hd*32+c
  if (row >= N) return;
  const float* tr = T + (long long)row * 32;
  float acc = 0.f;
#pragma unroll
  for (int c = 0; c < 32; ++c) acc += tr[c] * w[c * 64 + colx];
  int c = colx & 31, hd = colx >> 5;
  hh[(long long)row * 64 + c * 2 + hd] = (f16)acc;
}

// ---------- proj vectors ----------
__global__ void k_proj(const float* __restrict__ lin_w, const float* __restrict__ attl,
                       const float* __restrict__ attr, float* __restrict__ proj) {
  int t = threadIdx.x;
  if (t < 128) {
    int v = t >> 5, c = t & 31;
    int hd = v & 1;
    const float* att = (v < 2) ? attl : attr;
    float s = 0.f;
    for (int j = 0; j < 32; ++j) s += lin_w[c * 64 + hd * 32 + j] * att[hd * 32 + j];
    proj[v * 32 + c] = s;
  }
}

// ---------- per-node attention terms ----------
__global__ void k_nodeatt(const float* __restrict__ x, const float* __restrict__ proj,
                          float* __restrict__ natt, int N) {
  __shared__ float pj[128];
  if (threadIdx.x < 128) pj[threadIdx.x] = proj[threadIdx.x];
  __syncthreads();
  int g = (blockIdx.x * blockDim.x + threadIdx.x) >> 5;
  int c = threadIdx.x & 31;
  if (g >= N) return;
  float xv = x[(long long)g * 32 + c];
  float d0 = xv * pj[c], d1 = xv * pj[32 + c], d2 = xv * pj[64 + c], d3 = xv * pj[96 + c];
#pragma unroll
  for (int m = 16; m; m >>= 1) {
    d0 += __shfl_xor(d0, m, 32);
    d1 += __shfl_xor(d1, m, 32);
    d2 += __shfl_xor(d2, m, 32);
    d3 += __shfl_xor(d3, m, 32);
  }
  if (c == 0) *(float4*)(natt + (long long)g * 4) = make_float4(d0, d1, d2, d3);
}

// ---------- SuperGAT: wave/node, 8 edge slots x 8 lanes, per-slot online softmax ----------
__global__ void k_gat(const f16* __restrict__ h, const int* __restrict__ rowptr,
                      const int* __restrict__ col, const float* __restrict__ natt,
                      const float* __restrict__ gb, float* __restrict__ y,
                      float* __restrict__ bns, int N) {
  __shared__ float ls[64];
  if (threadIdx.x < 64) ls[threadIdx.x] = 0.f;
  __syncthreads();
  int wv = (blockIdx.x * blockDim.x + threadIdx.x) >> 6;
  int lane = threadIdx.x & 63;
  int e = lane >> 3, q = lane & 7;
  if (wv < N) {
    float4 own0, own1;
    unpack8(h + (long long)wv * 64 + q * 8, own0, own1);
    const float4 na = *(const float4*)(natt + (long long)wv * 4);  // {al0,al1,ar0,ar1}
    // self-loop alpha
    float d0 = own0.x * own0.x + own0.y * own0.y + own0.z * own0.z + own0.w * own0.w;
    float d1 = own1.x * own1.x + own1.y * own1.y + own1.z * own1.z + own1.w * own1.w;
#pragma unroll
    for (int m = 1; m <= 4; m <<= 1) { d0 += __shfl_xor(d0, m); d1 += __shfl_xor(d1, m); }
    float a0 = (na.x + na.z) / (1.f + __expf(-d0));
    float a1 = (na.y + na.w) / (1.f + __expf(-d1));
    a0 = (a0 > 0.f) ? a0 : 0.2f * a0;
    a1 = (a1 > 0.f) ? a1 : 0.2f * a1;
    // per-slot state (slot 0 seeds the self-loop)
    float m0, m1, l0, l1;
    float4 acc0, acc1;
    if (e == 0) {
      m0 = a0; m1 = a1; l0 = 1.f; l1 = 1.f;
      acc0 = own0; acc1 = own1;
    } else {
      m0 = -1e30f; m1 = -1e30f; l0 = 0.f; l1 = 0.f;
      acc0 = make_float4(0, 0, 0, 0); acc1 = make_float4(0, 0, 0, 0);
    }
    int lo = rowptr[wv], hi = rowptr[wv + 1];
    for (int j = lo; j < hi; j += 8) {
      int jj = j + e;
      bool valid = jj < hi;
      int s = col[valid ? jj : (hi - 1)];
      float4 h0, h1;
      unpack8(h + (long long)s * 64 + q * 8, h0, h1);
      float2 al = *(const float2*)(natt + (long long)s * 4);
      float t0 = h0.x * own0.x + h0.y * own0.y + h0.z * own0.z + h0.w * own0.w;
      float t1 = h1.x * own1.x + h1.y * own1.y + h1.z * own1.z + h1.w * own1.w;
#pragma unroll
      for (int m = 1; m <= 4; m <<= 1) { t0 += __shfl_xor(t0, m); t1 += __shfl_xor(t1, m); }
      float ae0 = (al.x + na.z) / (1.f + __expf(-t0));
      float ae1 = (al.y + na.w) / (1.f + __expf(-t1));
      ae0 = (ae0 > 0.f) ? ae0 : 0.2f * ae0;
      ae1 = (ae1 > 0.f) ? ae1 : 0.2f * ae1;
      if (valid) {
        float mn0 = fmaxf(m0, ae0), mn1 = fmaxf(m1, ae1);
        float sc0 = __expf(m0 - mn0), sc1 = __expf(m1 - mn1);
        float f0 = __expf(ae0 - mn0), f1 = __expf(ae1 - mn1);
        l0 = l0 * sc0 + f0;
        l1 = l1 * sc1 + f1;
        acc0.x = acc0.x * sc0 + f0 * h0.x; acc0.y = acc0.y * sc0 + f0 * h0.y;
        acc0.z = acc0.z * sc0 + f0 * h0.z; acc0.w = acc0.w * sc0 + f0 * h0.w;
        acc1.x = acc1.x * sc1 + f1 * h1.x; acc1.y = acc1.y * sc1 + f1 * h1.y;
        acc1.z = acc1.z * sc1 + f1 * h1.z; acc1.w = acc1.w * sc1 + f1 * h1.w;
        m0 = mn0; m1 = mn1;
      }
    }
    // merge the 8 slot states (flash-attention merge across lanes 8,16,32)
#pragma unroll
    for (int m = 8; m <= 32; m <<= 1) {
      float om0 = __shfl_xor(m0, m), om1 = __shfl_xor(m1, m);
      float ol0 = __shfl_xor(l0, m), ol1 = __shfl_xor(l1, m);
      float4 oa0 = make_float4(__shfl_xor(acc0.x, m), __shfl_xor(acc0.y, m),
                               __shfl_xor(acc0.z, m), __shfl_xor(acc0.w, m));
      float4 oa1 = make_float4(__shfl_xor(acc1.x, m), __shfl_xor(acc1.y, m),
                               __shfl_xor(acc1.z, m), __shfl_xor(acc1.w, m));
      float mn0 = fmaxf(m0, om0), mn1 = fmaxf(m1, om1);
      float fa0 = __expf(m0 - mn0), fb0 = __expf(om0 - mn0);
      float fa1 = __expf(m1 - mn1), fb1 = __expf(om1 - mn1);
      l0 = l0 * fa0 + ol0 * fb0;
      l1 = l1 * fa1 + ol1 * fb1;
      acc0.x = acc0.x * fa0 + oa0.x * fb0; acc0.y = acc0.y * fa0 + oa0.y * fb0;
      acc0.z = acc0.z * fa0 + oa0.z * fb0; acc0.w = acc0.w * fa0 + oa0.w * fb0;
      acc1.x = acc1.x * fa1 + oa1.x * fb1; acc1.y = acc1.y * fa1 + oa1.y * fb1;
      acc1.z = acc1.z * fa1 + oa1.z * fb1; acc1.w = acc1.w * fa1 + oa1.w * fb1;
      m0 = mn0; m1 = mn1;
    }
    if (e == 0) {
      float r0 = 1.f / l0, r1 = 1.f / l1;
      const float4 gb4 = *(const float4*)(gb + q * 4);
      float4 yv;
      float v;
      v = 0.5f * (acc0.x * r0 + acc1.x * r1) + gb4.x; yv.x = ((v > 0.f) ? v : 0.01f * v) + v;
      v = 0.5f * (acc0.y * r0 + acc1.y * r1) + gb4.y; yv.y = ((v > 0.f) ? v : 0.01f * v) + v;
      v = 0.5f * (acc0.z * r0 + acc1.z * r1) + gb4.z; yv.z = ((v > 0.f) ? v : 0.01f * v) + v;
      v = 0.5f * (acc0.w * r0 + acc1.w * r1) + gb4.w; yv.w = ((v > 0.f) ? v : 0.01f * v) + v;
      *(float4*)(y + (long long)wv * 32 + q * 4) = yv;
      atomicAdd(&ls[q * 4 + 0], yv.x); atomicAdd(&ls[32 + q * 4 + 0], yv.x * yv.x);
      atomicAdd(&ls[q * 4 + 1], yv.y); atomicAdd(&ls[32 + q * 4 + 1], yv.y * yv.y);
      atomicAdd(&ls[q * 4 + 2], yv.z); atomicAdd(&ls[32 + q * 4 + 2], yv.z * yv.z);
      atomicAdd(&ls[q * 4 + 3], yv.w); atomicAdd(&ls[32 + q * 4 + 3], yv.w * yv.w);
    }
  }
  __syncthreads();
  if (threadIdx.x < 64) atomicAdd(&bns[threadIdx.x], ls[threadIdx.x]);
}

__global__ void k_bnfinal(const float* __restrict__ y, const float* __restrict__ bns,
                          const float* __restrict__ g, const float* __restrict__ b,
                          float* __restrict__ out, int N) {
  int i = blockIdx.x * blockDim.x + threadIdx.x;
  if (i >= N * CC) return;
  int c = i & 31;
  float inv_n = 1.f / (float)N;
  float mu = bns[c] * inv_n;
  float var = bns[32 + c] * inv_n - mu * mu;
  out[i] = (y[i] - mu) * rsqrtf(var + 1e-5f) * g[c] + b[c];
}

extern "C" void kernel_launch(void* const* d_in, const int* in_sizes, int n_in,
                              void* d_out, int out_size, void* d_ws, size_t ws_size,
                              hipStream_t stream) {
  const float* patch = (const float*)d_in[0];
  const int* eidx = (const int*)d_in[1];
  const float* cheb_w = (const float*)d_in[3];
  const float* cheb_b = (const float*)d_in[4];
  const float* lin_w = (const float*)d_in[5];
  const float* att_l = (const float*)d_in[6];
  const float* att_r = (const float*)d_in[7];
  const float* gat_b = (const float*)d_in[8];
  const float* bn_g = (const float*)d_in[9];
  const float* bn_b = (const float*)d_in[10];
  float* out = (float*)d_out;

  const int N = in_sizes[0] / CC;  // 100000
  const int E = in_sizes[1] / 2;   // 1600000
  const int* src = eidx;
  const int* dst = eidx + E;

  // workspace (~47 MB)
  float* TxA = (float*)d_ws;                  // N*32 f (later hh[N*64 f16] overlays)
  float* TxB = TxA + (size_t)N * 32;          // N*32 f
  f16* xhA = (f16*)(TxB + (size_t)N * 32);    // N*32 f16
  f16* xhB = xhA + (size_t)N * 32;            // N*32 f16
  int* col = (int*)(xhB + (size_t)N * 32);    // E
  int* rowptr = col + E;                      // N+4
  int* cur = rowptr + N + 4;                  // N
  int* cnt = cur + N;                         // N
  float* deg = (float*)(cnt + N);             // N (dis in place)
  float* natt = deg + N;                      // N*4 (16B aligned)
  float* proj = natt + (size_t)N * 4;         // 128
  float* bns = proj + 128;                    // 64
  f16* hh = (f16*)TxA;                        // N*64 f16 == N*32 f

  const int B = 256;
  const long long NC = (long long)N * 32;

  hipMemsetAsync(cnt, 0, sizeof(int) * (size_t)N * 2, stream);  // cnt + deg
  hipMemsetAsync(bns, 0, sizeof(float) * 64, stream);

  // CSR + norm + fp16 patch
  k_cast<<<cdiv(NC, B), B, 0, stream>>>(patch, xhA, NC);
  k_degcnt<<<cdiv(E, B), B, 0, stream>>>(src, dst, deg, cnt, E);
  k_dis<<<cdiv(N, B), B, 0, stream>>>(deg, N);
  k_scan<<<1, 1024, 0, stream>>>(cnt, rowptr, cur, N);
  k_fill<<<cdiv(E, B), B, 0, stream>>>(src, dst, cur, col, E);

  // ChebConv (fused prop + gemm accumulate into d_out)
  // Tx1 = prop(Tx0): gather xhA(patch) -> TxA fp32, xhB f16
  k_prop<1><<<cdiv(NC, B), B, 0, stream>>>(xhA, patch, nullptr, rowptr, col, deg,
                                           cheb_w, cheb_b, TxA, xhB, out, 1.f, 0.f, N);
  // Tx2 = 2*prop(Tx1)-Tx0: gather xhB, prev=patch -> TxB, xhA
  k_prop<0><<<cdiv(NC, B), B, 0, stream>>>(xhB, nullptr, patch, rowptr, col, deg,
                                           cheb_w + 2 * 1024, nullptr, TxB, xhA, out, 2.f, -1.f, N);
  // Tx3 = 2*prop(Tx2)-Tx1: gather xhA, prev=TxA -> TxA, xhB
  k_prop<0><<<cdiv(NC, B), B, 0, stream>>>(xhA, nullptr, TxA, rowptr, col, deg,
                                           cheb_w + 3 * 1024, nullptr, TxA, xhB, out, 2.f, -1.f, N);
  // Tx4 = 2*prop(Tx3)-Tx2: gather xhB, prev=TxB -> TxB, (no f16 out)
  k_prop<0><<<cdiv(NC, B), B, 0, stream>>>(xhB, nullptr, TxB, rowptr, col, deg,
                                           cheb_w + 4 * 1024, nullptr, TxB, nullptr, out, 2.f, -1.f, N);

  // SuperGAT
  k_proj<<<1, 128, 0, stream>>>(lin_w, att_l, att_r, proj);
  k_nodeatt<<<cdiv(NC, B), B, 0, stream>>>(out, proj, natt, N);
  k_gemm64<<<cdiv(N, 4), B, 0, stream>>>(out, lin_w, hh, N);  // hh overlays TxA (dead)
  k_gat<<<cdiv(N, 4), B, 0, stream>>>(hh, rowptr, col, natt, gat_b, out, bns, N);

  // BatchNorm finalize (in place on d_out)
  k_bnfinal<<<cdiv(NC, B), B, 0, stream>>>(out, bns, bn_g, bn_b, out, N);
}